// Round 6
// baseline (187.639 us; speedup 1.0000x reference)
//
#include <hip/hip_runtime.h>
#include <hip/hip_bf16.h>

typedef __bf16 v8bf __attribute__((ext_vector_type(8)));
typedef float  v4f  __attribute__((ext_vector_type(4)));

typedef __attribute__((address_space(3))) void       lds_vd;
typedef __attribute__((address_space(1))) const void gbl_vd;

#define MFMA16(a, b, c) __builtin_amdgcn_mfma_f32_16x16x32_bf16(a, b, c, 0, 0, 0)

// hi/lo bf16 split of an fp32 value (hi = RN(v), lo = RN(v - hi))
__device__ __forceinline__ void split_hl(float v, __bf16* h, __bf16* l) {
    __bf16 hh = (__bf16)v;
    *h = hh;
    *l = (__bf16)(v - (float)hh);
}

// XOR-swizzled [R][64] bf16 LDS tiles: element (row,col) lives at
// row*64 + ((col>>3 ^ (row&7))<<3) + (col&7).
__device__ __forceinline__ int swz_idx(int row, int col) {
    return row * 64 + ((((col >> 3) ^ (row & 7))) << 3) + (col & 7);
}
__device__ __forceinline__ const __bf16* frag_ptr(const __bf16* base, int row, int g) {
    return base + row * 64 + ((g ^ (row & 7)) << 3);
}

// ---------------------------------------------------------------------------
// dims: fms_low [8][256][64][64] -> feat_low [8·4096][256] (flat view)
//       fms_high [8][512][32][32]; conv -> X [8][256][1024] = feat_high [8·1024][256]
//       ML [8·4096][64] hi/lo, MH [8·1024][64] hi/lo, VT [8][256][1024]
//       out [8][256][4096]
// ---------------------------------------------------------------------------

// ============ fused conv+BN+ReLU GEMM  ∥  proj32 GEMM (independent) ========
// Even blocks: conv tile (R3-verified body, verbatim).  Odd blocks: proj32
// tile (R3-verified body, verbatim).  The two consume different inputs
// (fms_high vs fms_low) and are data-independent -> running them in ONE
// dispatch interleaves their resident blocks 50/50 on every CU, so conv's
// barrier/VALU-staging stalls overlap with proj32's MFMA/memory phases
// instead of serializing on the stream.  Numerics bit-identical.
__global__ __launch_bounds__(256) void k_convproj(
    // conv operands
    const float* __restrict__ FH, const float* __restrict__ W,
    const float* __restrict__ gamma, const float* __restrict__ beta,
    const float* __restrict__ mean, const float* __restrict__ var,
    __bf16* __restrict__ Xhi, __bf16* __restrict__ Xlo, __bf16* __restrict__ VT,
    // proj32 operands
    const float* __restrict__ Feat, const float* __restrict__ W1,
    const float* __restrict__ b1,
    __bf16* __restrict__ MLhi, __bf16* __restrict__ MLlo)
{
    union SMem {
        struct {   // conv: 33 KB
            __bf16 Ah[4096], Al[4096], Bh[4096], Bl[4096];
            float invl[64], shl[64];
        } c;
        struct {   // proj32: 72 KB
            __bf16 Bh[16384], Bl[16384];
            __bf16 Eo[4][1024];
        } p;
    };
    __shared__ __align__(16) SMem sm;

    const int tid = threadIdx.x, lane = tid & 63, w = tid >> 6;
    const int l15 = lane & 15, quad = lane >> 4;
    const bool isconv = (blockIdx.x & 1) == 0;
    const int sub = blockIdx.x >> 1;            // 0..511 for each path

    if (isconv) {
        // =================== conv path (verbatim R3/R5 k_conv) =============
        __bf16* Ah = sm.c.Ah; __bf16* Al = sm.c.Al;
        __bf16* Bh = sm.c.Bh; __bf16* Bl = sm.c.Bl;
        float* invl = sm.c.invl; float* shl = sm.c.shl;

        const int u0 = (sub & 15) * 16, o0 = ((sub >> 4) & 3) * 64, b = sub >> 6;
        const float* FHb = FH + (size_t)b * 524288;

        if (tid < 64) {
            const int o = o0 + tid;
            const float iv = gamma[o] * rsqrtf(var[o] + 1e-5f);
            invl[tid] = iv;
            shl[tid] = beta[o] - mean[o] * iv;
        }

        const int ao = tid >> 2, aseg = tid & 3;
        float wreg[16], freg[16];
        {
            const float* wp = W + (size_t)(o0 + ao) * 512 + aseg * 16;
            #pragma unroll
            for (int q = 0; q < 4; ++q) {
                float4 f = ((const float4*)wp)[q];
                wreg[4*q] = f.x; wreg[4*q+1] = f.y; wreg[4*q+2] = f.z; wreg[4*q+3] = f.w;
            }
            const float* fp = FHb + (size_t)lane * 1024 + w * 256 + u0;
            #pragma unroll
            for (int q = 0; q < 4; ++q) {
                float4 f = ((const float4*)fp)[q];
                freg[4*q] = f.x; freg[4*q+1] = f.y; freg[4*q+2] = f.z; freg[4*q+3] = f.w;
            }
        }

        v4f acc[2][2];
        #pragma unroll
        for (int i = 0; i < 2; ++i)
            #pragma unroll
            for (int j = 0; j < 2; ++j) { v4f z = {0.f,0.f,0.f,0.f}; acc[i][j] = z; }
        const int oh = w >> 1, nh = w & 1;

        for (int ch = 0; ch < 8; ++ch) {
            if (ch) __syncthreads();
            #pragma unroll
            for (int z = 0; z < 2; ++z) {
                v8bf hv, lv;
                #pragma unroll
                for (int e = 0; e < 8; ++e) {
                    __bf16 h, l; split_hl(wreg[8*z + e], &h, &l);
                    hv[e] = h; lv[e] = l;
                }
                const int gi = (2*aseg + z) ^ (ao & 7);
                *(v8bf*)(Ah + ao*64 + (gi << 3)) = hv;
                *(v8bf*)(Al + ao*64 + (gi << 3)) = lv;
            }
            #pragma unroll
            for (int ul = 0; ul < 16; ++ul) {
                __bf16 h, l; split_hl(freg[ul], &h, &l);
                const int idx = (w*16 + ul)*64 + (((lane >> 3) ^ (ul & 7)) << 3) + (lane & 7);
                Bh[idx] = h; Bl[idx] = l;
            }
            __syncthreads();
            if (ch < 7) {
                const int c1 = (ch + 1) * 64;
                const float* wp = W + (size_t)(o0 + ao) * 512 + c1 + aseg * 16;
                #pragma unroll
                for (int q = 0; q < 4; ++q) {
                    float4 f = ((const float4*)wp)[q];
                    wreg[4*q] = f.x; wreg[4*q+1] = f.y; wreg[4*q+2] = f.z; wreg[4*q+3] = f.w;
                }
                const float* fp = FHb + (size_t)(c1 + lane) * 1024 + w * 256 + u0;
                #pragma unroll
                for (int q = 0; q < 4; ++q) {
                    float4 f = ((const float4*)fp)[q];
                    freg[4*q] = f.x; freg[4*q+1] = f.y; freg[4*q+2] = f.z; freg[4*q+3] = f.w;
                }
            }
            #pragma unroll
            for (int ks = 0; ks < 2; ++ks) {
                const int g = 4*ks + quad;
                v8bf a_h[2], a_l[2], b_h[2], b_l[2];
                #pragma unroll
                for (int i = 0; i < 2; ++i) {
                    const int row = oh*32 + i*16 + l15;
                    a_h[i] = *(const v8bf*)frag_ptr(Ah, row, g);
                    a_l[i] = *(const v8bf*)frag_ptr(Al, row, g);
                }
                #pragma unroll
                for (int j = 0; j < 2; ++j) {
                    const int row = nh*32 + j*16 + l15;
                    b_h[j] = *(const v8bf*)frag_ptr(Bh, row, g);
                    b_l[j] = *(const v8bf*)frag_ptr(Bl, row, g);
                }
                #pragma unroll
                for (int i = 0; i < 2; ++i)
                    #pragma unroll
                    for (int j = 0; j < 2; ++j) {
                        acc[i][j] = MFMA16(a_h[i], b_h[j], acc[i][j]);
                        acc[i][j] = MFMA16(a_h[i], b_l[j], acc[i][j]);
                        acc[i][j] = MFMA16(a_l[i], b_h[j], acc[i][j]);
                    }
            }
        }
        __syncthreads();

        #pragma unroll
        for (int i = 0; i < 2; ++i)
            #pragma unroll
            for (int j = 0; j < 2; ++j)
                #pragma unroll
                for (int r = 0; r < 4; ++r) {
                    const int row = oh*32 + i*16 + quad*4 + r;
                    const int col = nh*32 + j*16 + l15;
                    float v = acc[i][j][r] * invl[row] + shl[row];
                    v = fmaxf(v, 0.f);
                    __bf16 h, l; split_hl(v, &h, &l);
                    const int idx = swz_idx(row, col);
                    Ah[idx] = h; Al[idx] = l;
                }
        __syncthreads();
        {
            const int o = tid >> 2, pv = tid & 3;
            const size_t gbase = ((size_t)b*256 + o0 + o) * 1024 + pv*256 + u0;
            #pragma unroll
            for (int z = 0; z < 2; ++z) {
                const int gi = (2*pv + z) ^ (o & 7);
                v8bf h = *(v8bf*)(Ah + o*64 + (gi << 3));
                v8bf l = *(v8bf*)(Al + o*64 + (gi << 3));
                *(v8bf*)(Xhi + gbase + z*8) = h;
                *(v8bf*)(Xlo + gbase + z*8) = l;
            }
        }
        {
            const int ul = tid >> 4, s = tid & 15;
            __bf16 tmp[16];
            #pragma unroll
            for (int k = 0; k < 16; ++k) {
                const int m = s*16 + k;
                const int row = m >> 2;
                const int col = (m & 3)*16 + ul;
                tmp[k] = Ah[swz_idx(row, col)];
            }
            __bf16* vp = VT + ((size_t)b*256 + u0 + ul) * 1024 + 4*o0 + s*16;
            *(v8bf*)(vp)     = *(v8bf*)(tmp);
            *(v8bf*)(vp + 8) = *(v8bf*)(tmp + 8);
        }
    } else {
        // =================== proj32 path (verbatim R3/R5) ==================
        __bf16* Bh = sm.p.Bh; __bf16* Bl = sm.p.Bl;

        const int r0 = sub * 64;
        const int row = r0 + w*16 + l15;

        const float* ap = Feat + (size_t)row * 256 + quad * 8;
        float acur[8], anxt[8];
        {
            float4 f0 = ((const float4*)ap)[0];
            float4 f1 = ((const float4*)ap)[1];
            acur[0]=f0.x; acur[1]=f0.y; acur[2]=f0.z; acur[3]=f0.w;
            acur[4]=f1.x; acur[5]=f1.y; acur[6]=f1.z; acur[7]=f1.w;
        }

        {
            const int n = tid >> 2, q4 = tid & 3, n7 = n & 7;
            const float* wp = W1 + (size_t)n * 256 + q4 * 64;
            #pragma unroll
            for (int z = 0; z < 8; ++z) {
                float4 f0 = ((const float4*)wp)[2*z];
                float4 f1 = ((const float4*)wp)[2*z + 1];
                float w8[8] = {f0.x, f0.y, f0.z, f0.w, f1.x, f1.y, f1.z, f1.w};
                v8bf hv, lv;
                #pragma unroll
                for (int e = 0; e < 8; ++e) {
                    __bf16 h, l; split_hl(w8[e], &h, &l);
                    hv[e] = h; lv[e] = l;
                }
                const int gsw = (q4*8 + z) ^ n7;
                *(v8bf*)(Bh + n*256 + gsw*8) = hv;
                *(v8bf*)(Bl + n*256 + gsw*8) = lv;
            }
        }
        __syncthreads();

        v4f acc[4];
        #pragma unroll
        for (int j = 0; j < 4; ++j) { v4f z = {0.f,0.f,0.f,0.f}; acc[j] = z; }

        const int l7 = l15 & 7;
        const __bf16* bh_base = Bh + l15*256;
        const __bf16* bl_base = Bl + l15*256;

        #pragma unroll
        for (int kc = 0; kc < 8; ++kc) {
            if (kc < 7) {
                float4 f0 = ((const float4*)(ap + (kc+1)*32))[0];
                float4 f1 = ((const float4*)(ap + (kc+1)*32))[1];
                anxt[0]=f0.x; anxt[1]=f0.y; anxt[2]=f0.z; anxt[3]=f0.w;
                anxt[4]=f1.x; anxt[5]=f1.y; anxt[6]=f1.z; anxt[7]=f1.w;
            }
            v8bf ah, al;
            #pragma unroll
            for (int e = 0; e < 8; ++e) {
                __bf16 h, l; split_hl(acur[e], &h, &l);
                ah[e] = h; al[e] = l;
            }
            const int goff = (((kc*4 + quad) ^ l7) << 3);
            #pragma unroll
            for (int j = 0; j < 4; ++j) {
                v8bf bh = *(const v8bf*)(bh_base + j*4096 + goff);
                v8bf bl = *(const v8bf*)(bl_base + j*4096 + goff);
                acc[j] = MFMA16(ah, bh, acc[j]);
                acc[j] = MFMA16(ah, bl, acc[j]);
                acc[j] = MFMA16(al, bh, acc[j]);
            }
            #pragma unroll
            for (int e = 0; e < 8; ++e) acur[e] = anxt[e];
        }

        __bf16* eo = &sm.p.Eo[w][0];
        __bf16 lb[4][4];
        #pragma unroll
        for (int j = 0; j < 4; ++j) {
            const float bias = b1[j*16 + l15];
            #pragma unroll
            for (int r = 0; r < 4; ++r) {
                __bf16 h, l; split_hl(acc[j][r] + bias, &h, &l);
                lb[j][r] = l;
                eo[swz_idx(quad*4 + r, j*16 + l15)] = h;
            }
        }
        const size_t orow = (size_t)row * 64;
        #pragma unroll
        for (int z = 0; z < 2; ++z) {
            const int gi = (2*quad + z) ^ l7;
            *(v8bf*)(MLhi + orow + quad*16 + z*8) = *(v8bf*)(eo + l15*64 + gi*8);
        }
        #pragma unroll
        for (int j = 0; j < 4; ++j)
            #pragma unroll
            for (int r = 0; r < 4; ++r)
                eo[swz_idx(quad*4 + r, j*16 + l15)] = lb[j][r];
        #pragma unroll
        for (int z = 0; z < 2; ++z) {
            const int gi = (2*quad + z) ^ l7;
            *(v8bf*)(MLlo + orow + quad*16 + z*8) = *(v8bf*)(eo + l15*64 + gi*8);
        }
    }
}

// ============ projection, pre-split bf16 input (MH): [M][256] hi/lo ========
// (verbatim R3 k_projbf — depends on X from conv, so its own dispatch)
__global__ __launch_bounds__(256) void k_projbf(
    const __bf16* __restrict__ Fhi, const __bf16* __restrict__ Flo,
    const float* __restrict__ Wfc, const float* __restrict__ bfc,
    __bf16* __restrict__ Ohi, __bf16* __restrict__ Olo)
{
    __shared__ __align__(16) __bf16 Bh[64 * 256];
    __shared__ __align__(16) __bf16 Bl[64 * 256];
    __shared__ __align__(16) __bf16 Eo[4][16 * 64];

    const int tid = threadIdx.x, lane = tid & 63, w = tid >> 6;
    const int l15 = lane & 15, quad = lane >> 4;
    const int r0 = blockIdx.x * 64;
    const int row = r0 + w*16 + l15;

    const __bf16* fh = Fhi + (size_t)row * 256 + quad * 8;
    const __bf16* fl = Flo + (size_t)row * 256 + quad * 8;
    v8bf ah = *(const v8bf*)(fh);
    v8bf al = *(const v8bf*)(fl);

    {
        const int n = tid >> 2, q4 = tid & 3, n7 = n & 7;
        const float* wp = Wfc + (size_t)n * 256 + q4 * 64;
        #pragma unroll
        for (int z = 0; z < 8; ++z) {
            float4 f0 = ((const float4*)wp)[2*z];
            float4 f1 = ((const float4*)wp)[2*z + 1];
            float w8[8] = {f0.x, f0.y, f0.z, f0.w, f1.x, f1.y, f1.z, f1.w};
            v8bf hv, lv;
            #pragma unroll
            for (int e = 0; e < 8; ++e) {
                __bf16 h, l; split_hl(w8[e], &h, &l);
                hv[e] = h; lv[e] = l;
            }
            const int gsw = (q4*8 + z) ^ n7;
            *(v8bf*)(Bh + n*256 + gsw*8) = hv;
            *(v8bf*)(Bl + n*256 + gsw*8) = lv;
        }
    }
    __syncthreads();

    v4f acc[4];
    #pragma unroll
    for (int j = 0; j < 4; ++j) { v4f z = {0.f,0.f,0.f,0.f}; acc[j] = z; }

    const int l7 = l15 & 7;
    const __bf16* bh_base = Bh + l15*256;
    const __bf16* bl_base = Bl + l15*256;

    #pragma unroll
    for (int kc = 0; kc < 8; ++kc) {
        v8bf anh, anl;
        if (kc < 7) {
            anh = *(const v8bf*)(fh + (kc+1)*32);
            anl = *(const v8bf*)(fl + (kc+1)*32);
        }
        const int goff = (((kc*4 + quad) ^ l7) << 3);
        #pragma unroll
        for (int j = 0; j < 4; ++j) {
            v8bf bh = *(const v8bf*)(bh_base + j*4096 + goff);
            v8bf bl = *(const v8bf*)(bl_base + j*4096 + goff);
            acc[j] = MFMA16(ah, bh, acc[j]);
            acc[j] = MFMA16(ah, bl, acc[j]);
            acc[j] = MFMA16(al, bh, acc[j]);
        }
        if (kc < 7) { ah = anh; al = anl; }
    }

    __bf16* eo = &Eo[w][0];
    __bf16 lb[4][4];
    #pragma unroll
    for (int j = 0; j < 4; ++j) {
        const float bias = bfc[j*16 + l15];
        #pragma unroll
        for (int r = 0; r < 4; ++r) {
            __bf16 h, l; split_hl(acc[j][r] + bias, &h, &l);
            lb[j][r] = l;
            eo[swz_idx(quad*4 + r, j*16 + l15)] = h;
        }
    }
    const size_t orow = (size_t)row * 64;
    #pragma unroll
    for (int z = 0; z < 2; ++z) {
        const int gi = (2*quad + z) ^ l7;
        *(v8bf*)(Ohi + orow + quad*16 + z*8) = *(v8bf*)(eo + l15*64 + gi*8);
    }
    #pragma unroll
    for (int j = 0; j < 4; ++j)
        #pragma unroll
        for (int r = 0; r < 4; ++r)
            eo[swz_idx(quad*4 + r, j*16 + l15)] = lb[j][r];
    #pragma unroll
    for (int z = 0; z < 2; ++z) {
        const int gi = (2*quad + z) ^ l7;
        *(v8bf*)(Olo + orow + quad*16 + z*8) = *(v8bf*)(eo + l15*64 + gi*8);
    }
}

// ============================= flash attention =============================
// (verbatim R5 — 8-wave blocks, 1 barrier/chunk, wave-local V staging,
// vmcnt never drained to 0 in-loop, split QK chains.)
__global__ __launch_bounds__(512, 4) void k_attn(
    const __bf16* __restrict__ MLhi, const __bf16* __restrict__ MLlo,
    const __bf16* __restrict__ MHhi, const __bf16* __restrict__ MHlo,
    const __bf16* __restrict__ VT,   // [b][256][1024]
    const float* __restrict__ scale_p,
    float* __restrict__ out)
{
    __shared__ __align__(16) __bf16 Khi[2][32 * 64];   // 8 KB  [buf][m][k]
    __shared__ __align__(16) __bf16 Klo[2][32 * 64];   // 8 KB
    __shared__ __align__(16) __bf16 Vs [2][256 * 32];  // 32 KB [buf][c][m_local]
    __shared__ __align__(16) __bf16 Ps [2][4][16 * 32];// 8 KB  [buf][qt][q][m]
    __shared__ float lsh[2][4][16];                    // [mb][qt][row]

    const int tid = threadIdx.x, lane = tid & 63, w = tid >> 6;   // w: 0..7
    const int l15 = lane & 15, quad = lane >> 4;
    const int b = blockIdx.x & 7, qtb = blockIdx.x >> 3;
    const int q0 = qtb * 64;
    const int qt = w & 3, mb = w >> 2;

    v8bf qhi[2], qlo[2];
    {
        const __bf16* qp  = MLhi + ((size_t)(b*4096 + q0 + qt*16 + l15)) * 64;
        const __bf16* qlp = MLlo + ((size_t)(b*4096 + q0 + qt*16 + l15)) * 64;
        #pragma unroll
        for (int h = 0; h < 2; ++h) {
            qhi[h] = *(const v8bf*)(qp + h*32 + quad*8);
            qlo[h] = *(const v8bf*)(qlp + h*32 + quad*8);
        }
    }
    #pragma unroll
    for (int h = 0; h < 2; ++h) {
        asm volatile("" : "+v"(qhi[h]));
        asm volatile("" : "+v"(qlo[h]));
    }

    const char* Khg = (const char*)(MHhi + (size_t)b * 65536);
    const char* Klg = (const char*)(MHlo + (size_t)b * 65536);
    const char* Vg  = (const char*)(VT + (size_t)b * 262144);
    const int offK = (lane >> 3) * 128 + (((lane & 7) ^ ((lane >> 3) & 7)) << 4);
    const int offV = (lane >> 2) * 2048 + ((((lane & 3) ^ ((lane >> 3) & 3))) << 4);

    const char* kgsrc = (w < 4) ? Khg : Klg;           // waves 0-3: hi, 4-7: lo
    const int ksub = (w & 3) * 1024;                   // 8-row slice

    v4f oacc[4][2];
    #pragma unroll
    for (int t = 0; t < 4; ++t)
        #pragma unroll
        for (int cb = 0; cb < 2; ++cb) { v4f z = {0.f,0.f,0.f,0.f}; oacc[t][cb] = z; }
    float lrow[4] = {0.f, 0.f, 0.f, 0.f};

    {
        char* kdst = (char*)((w < 4) ? &Khi[0][0] : &Klo[0][0]);
        __builtin_amdgcn_global_load_lds((gbl_vd*)(kgsrc + ksub + offK),
                                         (lds_vd*)(kdst + ksub), 16, 0, 0);
        #pragma unroll
        for (int j = 0; j < 2; ++j) {
            const int i = w*2 + j;
            __builtin_amdgcn_global_load_lds((gbl_vd*)(Vg + i*32768 + offV),
                                             (lds_vd*)((char*)&Vs[0][0] + i*1024), 16, 0, 0);
        }
    }
    asm volatile("s_waitcnt vmcnt(2)\n\ts_barrier" ::: "memory");

    for (int ch = 0; ch < 32; ++ch) {
        const int cur = ch & 1, nxt = cur ^ 1;
        const int mn = ((ch < 31) ? (ch + 1) : 31) * 32;

        {
            char* kdst = (char*)((w < 4) ? &Khi[nxt][0] : &Klo[nxt][0]);
            __builtin_amdgcn_global_load_lds((gbl_vd*)(kgsrc + mn*128 + ksub + offK),
                                             (lds_vd*)(kdst + ksub), 16, 0, 0);
        }

        // QK(ch): two independent 3-chains, combined at the end
        v4f s0 = {0.f, 0.f, 0.f, 0.f}, s1 = {0.f, 0.f, 0.f, 0.f};
        __builtin_amdgcn_s_setprio(1);
        {
            const int row = mb*16 + l15;
            v8bf kh0 = *(const v8bf*)frag_ptr(&Khi[cur][0], row, quad);
            v8bf kl0 = *(const v8bf*)frag_ptr(&Klo[cur][0], row, quad);
            v8bf kh1 = *(const v8bf*)frag_ptr(&Khi[cur][0], row, 4 + quad);
            v8bf kl1 = *(const v8bf*)frag_ptr(&Klo[cur][0], row, 4 + quad);
            s0 = MFMA16(qhi[0], kh0, s0);
            s1 = MFMA16(qhi[1], kh1, s1);
            s0 = MFMA16(qhi[0], kl0, s0);
            s1 = MFMA16(qhi[1], kl1, s1);
            s0 = MFMA16(qlo[0], kh0, s0);
            s1 = MFMA16(qlo[1], kh1, s1);
        }
        __builtin_amdgcn_s_setprio(0);
        v4f sacc = s0 + s1;

        #pragma unroll
        for (int r = 0; r < 4; ++r) {
            const float p = __expf(sacc[r]);
            lrow[r] += p;
            const int row = quad*4 + r;
            const int slot = (mb*2 + (l15 >> 3)) ^ ((row >> 1) & 3);
            Ps[cur][qt][row*32 + (slot << 3) + (l15 & 7)] = (__bf16)p;
        }

        if (ch) {
            const int pb = nxt;   // (ch-1)&1
            v8bf pa[4];
            #pragma unroll
            for (int t = 0; t < 4; ++t)
                pa[t] = *(const v8bf*)(&Ps[pb][t][0] + l15*32 + ((quad ^ ((l15 >> 1) & 3)) << 3));
            __builtin_amdgcn_s_setprio(1);
            #pragma unroll
            for (int cb = 0; cb < 2; ++cb) {
                const int vrow = w*32 + cb*16 + l15;
                v8bf vv = *(const v8bf*)(&Vs[pb][0] + vrow*32 + ((quad ^ ((vrow >> 1) & 3)) << 3));
                #pragma unroll
                for (int t = 0; t < 4; ++t)
                    oacc[t][cb] = MFMA16(pa[t], vv, oacc[t][cb]);
            }
            __builtin_amdgcn_s_setprio(0);
        }

        asm volatile("s_waitcnt lgkmcnt(0)" ::: "memory");
        #pragma unroll
        for (int j = 0; j < 2; ++j) {
            const int i = w*2 + j;
            __builtin_amdgcn_global_load_lds((gbl_vd*)(Vg + mn*2 + i*32768 + offV),
                                             (lds_vd*)((char*)&Vs[nxt][0] + i*1024), 16, 0, 0);
        }

        asm volatile("s_waitcnt vmcnt(2) lgkmcnt(0)\n\ts_barrier" ::: "memory");
    }

    {
        v8bf pa[4];
        #pragma unroll
        for (int t = 0; t < 4; ++t)
            pa[t] = *(const v8bf*)(&Ps[1][t][0] + l15*32 + ((quad ^ ((l15 >> 1) & 3)) << 3));
        #pragma unroll
        for (int cb = 0; cb < 2; ++cb) {
            const int vrow = w*32 + cb*16 + l15;
            v8bf vv = *(const v8bf*)(&Vs[1][0] + vrow*32 + ((quad ^ ((vrow >> 1) & 3)) << 3));
            #pragma unroll
            for (int t = 0; t < 4; ++t)
                oacc[t][cb] = MFMA16(pa[t], vv, oacc[t][cb]);
        }
    }

    #pragma unroll
    for (int r = 0; r < 4; ++r) {
        float s = lrow[r];
        #pragma unroll
        for (int d = 1; d < 16; d <<= 1) s += __shfl_xor(s, d, 64);
        lrow[r] = s;
    }
    if (l15 == 0) {
        #pragma unroll
        for (int r = 0; r < 4; ++r) lsh[mb][qt][quad*4 + r] = lrow[r];
    }
    __syncthreads();

    const float scl = scale_p[0];
    float inv[4][4];
    #pragma unroll
    for (int t = 0; t < 4; ++t)
        #pragma unroll
        for (int r = 0; r < 4; ++r)
            inv[t][r] = scl / (lsh[0][t][quad*4 + r] + lsh[1][t][quad*4 + r]);
    float* outb = out + (size_t)b * 256 * 4096;
    #pragma unroll
    for (int cb = 0; cb < 2; ++cb) {
        const int c = w*32 + cb*16 + l15;
        #pragma unroll
        for (int t = 0; t < 4; ++t) {
            float4 v;
            v.x = oacc[t][cb][0] * inv[t][0];
            v.y = oacc[t][cb][1] * inv[t][1];
            v.z = oacc[t][cb][2] * inv[t][2];
            v.w = oacc[t][cb][3] * inv[t][3];
            *(float4*)(outb + (size_t)c * 4096 + q0 + t*16 + quad*4) = v;
        }
    }
}

// ===========================================================================
extern "C" void kernel_launch(void* const* d_in, const int* in_sizes, int n_in,
                              void* d_out, int out_size, void* d_ws, size_t ws_size,
                              hipStream_t stream)
{
    const float* fms_low  = (const float*)d_in[0];
    const float* fms_high = (const float*)d_in[1];
    const float* w_conv   = (const float*)d_in[2];
    const float* gamma    = (const float*)d_in[3];
    const float* beta     = (const float*)d_in[4];
    const float* mean     = (const float*)d_in[5];
    const float* var      = (const float*)d_in[6];
    const float* fc1_w    = (const float*)d_in[7];
    const float* fc1_b    = (const float*)d_in[8];
    const float* fc2_w    = (const float*)d_in[9];
    const float* fc2_b    = (const float*)d_in[10];
    const float* scale    = (const float*)d_in[11];
    float* out = (float*)d_out;

    __bf16* Xhi  = (__bf16*)d_ws;
    __bf16* Xlo  = Xhi  + (size_t)8*256*1024;
    __bf16* VT   = Xlo  + (size_t)8*256*1024;
    __bf16* MLhi = VT   + (size_t)8*256*1024;
    __bf16* MLlo = MLhi + (size_t)8*4096*64;
    __bf16* MHhi = MLlo + (size_t)8*4096*64;
    __bf16* MHlo = MHhi + (size_t)8*1024*64;

    k_convproj<<<dim3(1024), 256, 0, stream>>>(fms_high, w_conv, gamma, beta,
                                               mean, var, Xhi, Xlo, VT,
                                               fms_low, fc1_w, fc1_b, MLhi, MLlo);
    k_projbf<<<dim3(128), 256, 0, stream>>>(Xhi, Xlo, fc2_w, fc2_b, MHhi, MHlo);
    k_attn<<<dim3(512), 512, 0, stream>>>(MLhi, MLlo, MHhi, MHlo, VT, scale, out);
}

// Round 7
// 178.934 us; speedup vs baseline: 1.0487x; 1.0487x over previous
//
#include <hip/hip_runtime.h>
#include <hip/hip_bf16.h>

typedef __bf16 v8bf __attribute__((ext_vector_type(8)));
typedef float  v4f  __attribute__((ext_vector_type(4)));

typedef __attribute__((address_space(3))) void       lds_vd;
typedef __attribute__((address_space(1))) const void gbl_vd;

#define MFMA16(a, b, c) __builtin_amdgcn_mfma_f32_16x16x32_bf16(a, b, c, 0, 0, 0)

// hi/lo bf16 split of an fp32 value (hi = RN(v), lo = RN(v - hi))
__device__ __forceinline__ void split_hl(float v, __bf16* h, __bf16* l) {
    __bf16 hh = (__bf16)v;
    *h = hh;
    *l = (__bf16)(v - (float)hh);
}

// XOR-swizzled [R][64] bf16 LDS tiles: element (row,col) lives at
// row*64 + ((col>>3 ^ (row&7))<<3) + (col&7).
__device__ __forceinline__ int swz_idx(int row, int col) {
    return row * 64 + ((((col >> 3) ^ (row & 7))) << 3) + (col & 7);
}
__device__ __forceinline__ const __bf16* frag_ptr(const __bf16* base, int row, int g) {
    return base + row * 64 + ((g ^ (row & 7)) << 3);
}

// ---------------------------------------------------------------------------
// dims: fms_low [8][256][64][64] -> feat_low [8·4096][256] (flat view)
//       fms_high [8][512][32][32]; conv -> X [8][256][1024] = feat_high [8·1024][256]
//       ML [8·4096][64] hi/lo, MH [8·1024][64] hi/lo, VT [8][256][1024]
//       out [8][256][4096]
// ---------------------------------------------------------------------------

// ================= conv + BN + ReLU (hi/lo bf16 MFMA GEMM) =================
// (R3/R5-verified version, verbatim — fusion with proj reverted after R6
// showed the 72 KB union LDS crushed occupancy.)
__global__ __launch_bounds__(256) void k_conv(
    const float* __restrict__ FH, const float* __restrict__ W,
    const float* __restrict__ gamma, const float* __restrict__ beta,
    const float* __restrict__ mean, const float* __restrict__ var,
    __bf16* __restrict__ Xhi, __bf16* __restrict__ Xlo, __bf16* __restrict__ VT)
{
    __shared__ __align__(16) __bf16 Ah[64 * 64];  // W tile hi
    __shared__ __align__(16) __bf16 Al[64 * 64];
    __shared__ __align__(16) __bf16 Bh[64 * 64];  // FH^T tile hi (rows n = pv*16+ul)
    __shared__ __align__(16) __bf16 Bl[64 * 64];
    __shared__ float invl[64], shl[64];

    const int tid = threadIdx.x, lane = tid & 63, w = tid >> 6;
    const int l15 = lane & 15, quad = lane >> 4;
    const int u0 = blockIdx.x * 16, o0 = blockIdx.y * 64, b = blockIdx.z;
    const float* FHb = FH + (size_t)b * 524288;

    if (tid < 64) {
        const int o = o0 + tid;
        const float iv = gamma[o] * rsqrtf(var[o] + 1e-5f);
        invl[tid] = iv;
        shl[tid] = beta[o] - mean[o] * iv;
    }

    const int ao = tid >> 2, aseg = tid & 3;   // A staging: W row, 16-col segment
    float wreg[16], freg[16];
    {   // prefetch chunk 0
        const float* wp = W + (size_t)(o0 + ao) * 512 + aseg * 16;
        #pragma unroll
        for (int q = 0; q < 4; ++q) {
            float4 f = ((const float4*)wp)[q];
            wreg[4*q] = f.x; wreg[4*q+1] = f.y; wreg[4*q+2] = f.z; wreg[4*q+3] = f.w;
        }
        const float* fp = FHb + (size_t)lane * 1024 + w * 256 + u0;
        #pragma unroll
        for (int q = 0; q < 4; ++q) {
            float4 f = ((const float4*)fp)[q];
            freg[4*q] = f.x; freg[4*q+1] = f.y; freg[4*q+2] = f.z; freg[4*q+3] = f.w;
        }
    }

    v4f acc[2][2];
    #pragma unroll
    for (int i = 0; i < 2; ++i)
        #pragma unroll
        for (int j = 0; j < 2; ++j) { v4f z = {0.f,0.f,0.f,0.f}; acc[i][j] = z; }
    const int oh = w >> 1, nh = w & 1;

    for (int ch = 0; ch < 8; ++ch) {
        if (ch) __syncthreads();
        #pragma unroll
        for (int z = 0; z < 2; ++z) {
            v8bf hv, lv;
            #pragma unroll
            for (int e = 0; e < 8; ++e) {
                __bf16 h, l; split_hl(wreg[8*z + e], &h, &l);
                hv[e] = h; lv[e] = l;
            }
            const int gi = (2*aseg + z) ^ (ao & 7);
            *(v8bf*)(Ah + ao*64 + (gi << 3)) = hv;
            *(v8bf*)(Al + ao*64 + (gi << 3)) = lv;
        }
        #pragma unroll
        for (int ul = 0; ul < 16; ++ul) {
            __bf16 h, l; split_hl(freg[ul], &h, &l);
            const int idx = (w*16 + ul)*64 + (((lane >> 3) ^ (ul & 7)) << 3) + (lane & 7);
            Bh[idx] = h; Bl[idx] = l;
        }
        __syncthreads();
        if (ch < 7) {
            const int c1 = (ch + 1) * 64;
            const float* wp = W + (size_t)(o0 + ao) * 512 + c1 + aseg * 16;
            #pragma unroll
            for (int q = 0; q < 4; ++q) {
                float4 f = ((const float4*)wp)[q];
                wreg[4*q] = f.x; wreg[4*q+1] = f.y; wreg[4*q+2] = f.z; wreg[4*q+3] = f.w;
            }
            const float* fp = FHb + (size_t)(c1 + lane) * 1024 + w * 256 + u0;
            #pragma unroll
            for (int q = 0; q < 4; ++q) {
                float4 f = ((const float4*)fp)[q];
                freg[4*q] = f.x; freg[4*q+1] = f.y; freg[4*q+2] = f.z; freg[4*q+3] = f.w;
            }
        }
        #pragma unroll
        for (int ks = 0; ks < 2; ++ks) {
            const int g = 4*ks + quad;
            v8bf a_h[2], a_l[2], b_h[2], b_l[2];
            #pragma unroll
            for (int i = 0; i < 2; ++i) {
                const int row = oh*32 + i*16 + l15;
                a_h[i] = *(const v8bf*)frag_ptr(Ah, row, g);
                a_l[i] = *(const v8bf*)frag_ptr(Al, row, g);
            }
            #pragma unroll
            for (int j = 0; j < 2; ++j) {
                const int row = nh*32 + j*16 + l15;
                b_h[j] = *(const v8bf*)frag_ptr(Bh, row, g);
                b_l[j] = *(const v8bf*)frag_ptr(Bl, row, g);
            }
            #pragma unroll
            for (int i = 0; i < 2; ++i)
                #pragma unroll
                for (int j = 0; j < 2; ++j) {
                    acc[i][j] = MFMA16(a_h[i], b_h[j], acc[i][j]);
                    acc[i][j] = MFMA16(a_h[i], b_l[j], acc[i][j]);
                    acc[i][j] = MFMA16(a_l[i], b_h[j], acc[i][j]);
                }
        }
    }
    __syncthreads();

    #pragma unroll
    for (int i = 0; i < 2; ++i)
        #pragma unroll
        for (int j = 0; j < 2; ++j)
            #pragma unroll
            for (int r = 0; r < 4; ++r) {
                const int row = oh*32 + i*16 + quad*4 + r;
                const int col = nh*32 + j*16 + l15;
                float v = acc[i][j][r] * invl[row] + shl[row];
                v = fmaxf(v, 0.f);
                __bf16 h, l; split_hl(v, &h, &l);
                const int idx = swz_idx(row, col);
                Ah[idx] = h; Al[idx] = l;
            }
    __syncthreads();
    {
        const int o = tid >> 2, pv = tid & 3;
        const size_t gbase = ((size_t)b*256 + o0 + o) * 1024 + pv*256 + u0;
        #pragma unroll
        for (int z = 0; z < 2; ++z) {
            const int gi = (2*pv + z) ^ (o & 7);
            v8bf h = *(v8bf*)(Ah + o*64 + (gi << 3));
            v8bf l = *(v8bf*)(Al + o*64 + (gi << 3));
            *(v8bf*)(Xhi + gbase + z*8) = h;
            *(v8bf*)(Xlo + gbase + z*8) = l;
        }
    }
    {
        const int ul = tid >> 4, s = tid & 15;
        __bf16 tmp[16];
        #pragma unroll
        for (int k = 0; k < 16; ++k) {
            const int m = s*16 + k;
            const int row = m >> 2;
            const int col = (m & 3)*16 + ul;
            tmp[k] = Ah[swz_idx(row, col)];
        }
        __bf16* vp = VT + ((size_t)b*256 + u0 + ul) * 1024 + 4*o0 + s*16;
        *(v8bf*)(vp)     = *(v8bf*)(tmp);
        *(v8bf*)(vp + 8) = *(v8bf*)(tmp + 8);
    }
}

// ================ merged projections, 8-wave blocks (TLP x2) ===============
// R6 counters showed the proj kernels latency-bound at <=2 waves/SIMD.  New
// shape: 512 threads = 8 waves x 16 rows = 128 rows/block; grid 320
// (blocks 0..255 -> ML from fms_low/fc1, 256..319 -> MH from X/fc2).
// W staged to LDS once per block now serves 8 waves (half the staging work),
// and TLP doubles to 4 waves/SIMD.  Per-row staging layout / fragment reads /
// MFMA order / epilogue are verbatim from the R3-verified kernels ->
// ML/MH bit-identical.  LDS 80 KB (W hi/lo 64 + Eo 16).
__global__ __launch_bounds__(512) void k_proj(
    const float* __restrict__ Feat,                     // ML A (fp32)
    const __bf16* __restrict__ Fhi, const __bf16* __restrict__ Flo,  // MH A
    const float* __restrict__ W1, const float* __restrict__ b1,
    const float* __restrict__ W2, const float* __restrict__ b2,
    __bf16* __restrict__ O1hi, __bf16* __restrict__ O1lo,
    __bf16* __restrict__ O2hi, __bf16* __restrict__ O2lo)
{
    __shared__ __align__(16) __bf16 Bh[64 * 256];   // 32 KB  [n][k granule-swz]
    __shared__ __align__(16) __bf16 Bl[64 * 256];   // 32 KB
    __shared__ __align__(16) __bf16 Eo[8][16 * 64]; // 16 KB  per-wave epilogue

    const int tid = threadIdx.x, lane = tid & 63, w = tid >> 6;   // w: 0..7
    const int l15 = lane & 15, quad = lane >> 4;
    const bool low = blockIdx.x < 256;
    const int r0 = (low ? blockIdx.x : (blockIdx.x - 256)) * 128;
    const int row = r0 + w*16 + l15;

    const float* Wfc = low ? W1 : W2;
    const float* bfc = low ? b1 : b2;
    __bf16* Ohi = low ? O1hi : O2hi;
    __bf16* Olo = low ? O1lo : O2lo;

    // ---- stage W (64x256 fp32) -> Bh/Bl once.  512 threads: row n = t>>3,
    // k-eighth q8 = t&7 (32 floats).  granule g = q8*4+z, swz g^(n&7) —
    // final layout identical to the 256-thread version.
    {
        const int n = tid >> 3, q8 = tid & 7, n7 = n & 7;
        const float* wp = Wfc + (size_t)n * 256 + q8 * 32;
        #pragma unroll
        for (int z = 0; z < 4; ++z) {
            float4 f0 = ((const float4*)wp)[2*z];
            float4 f1 = ((const float4*)wp)[2*z + 1];
            float w8[8] = {f0.x, f0.y, f0.z, f0.w, f1.x, f1.y, f1.z, f1.w};
            v8bf hv, lv;
            #pragma unroll
            for (int e = 0; e < 8; ++e) {
                __bf16 h, l; split_hl(w8[e], &h, &l);
                hv[e] = h; lv[e] = l;
            }
            const int gsw = (q8*4 + z) ^ n7;
            *(v8bf*)(Bh + n*256 + gsw*8) = hv;
            *(v8bf*)(Bl + n*256 + gsw*8) = lv;
        }
    }
    __syncthreads();   // only barrier: B visible; read-only afterwards

    v4f acc[4];
    #pragma unroll
    for (int j = 0; j < 4; ++j) { v4f z = {0.f,0.f,0.f,0.f}; acc[j] = z; }

    const int l7 = l15 & 7;
    const __bf16* bh_base = Bh + l15*256;
    const __bf16* bl_base = Bl + l15*256;

    if (low) {
        // ---- fp32-A K-loop (split in regs) — verbatim R3 body
        const float* ap = Feat + (size_t)row * 256 + quad * 8;
        float acur[8], anxt[8];
        {
            float4 f0 = ((const float4*)ap)[0];
            float4 f1 = ((const float4*)ap)[1];
            acur[0]=f0.x; acur[1]=f0.y; acur[2]=f0.z; acur[3]=f0.w;
            acur[4]=f1.x; acur[5]=f1.y; acur[6]=f1.z; acur[7]=f1.w;
        }
        #pragma unroll
        for (int kc = 0; kc < 8; ++kc) {
            if (kc < 7) {
                float4 f0 = ((const float4*)(ap + (kc+1)*32))[0];
                float4 f1 = ((const float4*)(ap + (kc+1)*32))[1];
                anxt[0]=f0.x; anxt[1]=f0.y; anxt[2]=f0.z; anxt[3]=f0.w;
                anxt[4]=f1.x; anxt[5]=f1.y; anxt[6]=f1.z; anxt[7]=f1.w;
            }
            v8bf ah, al;
            #pragma unroll
            for (int e = 0; e < 8; ++e) {
                __bf16 h, l; split_hl(acur[e], &h, &l);
                ah[e] = h; al[e] = l;
            }
            const int goff = (((kc*4 + quad) ^ l7) << 3);
            #pragma unroll
            for (int j = 0; j < 4; ++j) {
                v8bf bh = *(const v8bf*)(bh_base + j*4096 + goff);
                v8bf bl = *(const v8bf*)(bl_base + j*4096 + goff);
                acc[j] = MFMA16(ah, bh, acc[j]);
                acc[j] = MFMA16(ah, bl, acc[j]);
                acc[j] = MFMA16(al, bh, acc[j]);
            }
            #pragma unroll
            for (int e = 0; e < 8; ++e) acur[e] = anxt[e];
        }
    } else {
        // ---- pre-split bf16-A K-loop — verbatim R3 body
        const __bf16* fh = Fhi + (size_t)row * 256 + quad * 8;
        const __bf16* fl = Flo + (size_t)row * 256 + quad * 8;
        v8bf ah = *(const v8bf*)(fh);
        v8bf al = *(const v8bf*)(fl);
        #pragma unroll
        for (int kc = 0; kc < 8; ++kc) {
            v8bf anh, anl;
            if (kc < 7) {
                anh = *(const v8bf*)(fh + (kc+1)*32);
                anl = *(const v8bf*)(fl + (kc+1)*32);
            }
            const int goff = (((kc*4 + quad) ^ l7) << 3);
            #pragma unroll
            for (int j = 0; j < 4; ++j) {
                v8bf bh = *(const v8bf*)(bh_base + j*4096 + goff);
                v8bf bl = *(const v8bf*)(bl_base + j*4096 + goff);
                acc[j] = MFMA16(ah, bh, acc[j]);
                acc[j] = MFMA16(ah, bl, acc[j]);
                acc[j] = MFMA16(al, bh, acc[j]);
            }
            if (kc < 7) { ah = anh; al = anl; }
        }
    }

    // ---- epilogue: bias, hi/lo split, per-wave LDS transpose, store
    __bf16* eo = &Eo[w][0];
    __bf16 lb[4][4];
    #pragma unroll
    for (int j = 0; j < 4; ++j) {
        const float bias = bfc[j*16 + l15];
        #pragma unroll
        for (int r = 0; r < 4; ++r) {
            __bf16 h, l; split_hl(acc[j][r] + bias, &h, &l);
            lb[j][r] = l;
            eo[swz_idx(quad*4 + r, j*16 + l15)] = h;
        }
    }
    const size_t orow = (size_t)row * 64;
    #pragma unroll
    for (int z = 0; z < 2; ++z) {
        const int gi = (2*quad + z) ^ l7;
        *(v8bf*)(Ohi + orow + quad*16 + z*8) = *(v8bf*)(eo + l15*64 + gi*8);
    }
    #pragma unroll
    for (int j = 0; j < 4; ++j)
        #pragma unroll
        for (int r = 0; r < 4; ++r)
            eo[swz_idx(quad*4 + r, j*16 + l15)] = lb[j][r];
    #pragma unroll
    for (int z = 0; z < 2; ++z) {
        const int gi = (2*quad + z) ^ l7;
        *(v8bf*)(Olo + orow + quad*16 + z*8) = *(v8bf*)(eo + l15*64 + gi*8);
    }
}

// ============================= flash attention =============================
// (verbatim R5 — 8-wave blocks, 1 barrier/chunk, wave-local V staging,
// vmcnt never drained to 0 in-loop, split QK chains.)
__global__ __launch_bounds__(512, 4) void k_attn(
    const __bf16* __restrict__ MLhi, const __bf16* __restrict__ MLlo,
    const __bf16* __restrict__ MHhi, const __bf16* __restrict__ MHlo,
    const __bf16* __restrict__ VT,   // [b][256][1024]
    const float* __restrict__ scale_p,
    float* __restrict__ out)
{
    __shared__ __align__(16) __bf16 Khi[2][32 * 64];   // 8 KB  [buf][m][k]
    __shared__ __align__(16) __bf16 Klo[2][32 * 64];   // 8 KB
    __shared__ __align__(16) __bf16 Vs [2][256 * 32];  // 32 KB [buf][c][m_local]
    __shared__ __align__(16) __bf16 Ps [2][4][16 * 32];// 8 KB  [buf][qt][q][m]
    __shared__ float lsh[2][4][16];                    // [mb][qt][row]

    const int tid = threadIdx.x, lane = tid & 63, w = tid >> 6;   // w: 0..7
    const int l15 = lane & 15, quad = lane >> 4;
    const int b = blockIdx.x & 7, qtb = blockIdx.x >> 3;
    const int q0 = qtb * 64;
    const int qt = w & 3, mb = w >> 2;

    v8bf qhi[2], qlo[2];
    {
        const __bf16* qp  = MLhi + ((size_t)(b*4096 + q0 + qt*16 + l15)) * 64;
        const __bf16* qlp = MLlo + ((size_t)(b*4096 + q0 + qt*16 + l15)) * 64;
        #pragma unroll
        for (int h = 0; h < 2; ++h) {
            qhi[h] = *(const v8bf*)(qp + h*32 + quad*8);
            qlo[h] = *(const v8bf*)(qlp + h*32 + quad*8);
        }
    }
    #pragma unroll
    for (int h = 0; h < 2; ++h) {
        asm volatile("" : "+v"(qhi[h]));
        asm volatile("" : "+v"(qlo[h]));
    }

    const char* Khg = (const char*)(MHhi + (size_t)b * 65536);
    const char* Klg = (const char*)(MHlo + (size_t)b * 65536);
    const char* Vg  = (const char*)(VT + (size_t)b * 262144);
    const int offK = (lane >> 3) * 128 + (((lane & 7) ^ ((lane >> 3) & 7)) << 4);
    const int offV = (lane >> 2) * 2048 + ((((lane & 3) ^ ((lane >> 3) & 3))) << 4);

    const char* kgsrc = (w < 4) ? Khg : Klg;           // waves 0-3: hi, 4-7: lo
    const int ksub = (w & 3) * 1024;                   // 8-row slice

    v4f oacc[4][2];
    #pragma unroll
    for (int t = 0; t < 4; ++t)
        #pragma unroll
        for (int cb = 0; cb < 2; ++cb) { v4f z = {0.f,0.f,0.f,0.f}; oacc[t][cb] = z; }
    float lrow[4] = {0.f, 0.f, 0.f, 0.f};

    {
        char* kdst = (char*)((w < 4) ? &Khi[0][0] : &Klo[0][0]);
        __builtin_amdgcn_global_load_lds((gbl_vd*)(kgsrc + ksub + offK),
                                         (lds_vd*)(kdst + ksub), 16, 0, 0);
        #pragma unroll
        for (int j = 0; j < 2; ++j) {
            const int i = w*2 + j;
            __builtin_amdgcn_global_load_lds((gbl_vd*)(Vg + i*32768 + offV),
                                             (lds_vd*)((char*)&Vs[0][0] + i*1024), 16, 0, 0);
        }
    }
    asm volatile("s_waitcnt vmcnt(2)\n\ts_barrier" ::: "memory");

    for (int ch = 0; ch < 32; ++ch) {
        const int cur = ch & 1, nxt = cur ^ 1;
        const int mn = ((ch < 31) ? (ch + 1) : 31) * 32;

        {
            char* kdst = (char*)((w < 4) ? &Khi[nxt][0] : &Klo[nxt][0]);
            __builtin_amdgcn_global_load_lds((gbl_vd*)(kgsrc + mn*128 + ksub + offK),
                                             (lds_vd*)(kdst + ksub), 16, 0, 0);
        }

        // QK(ch): two independent 3-chains, combined at the end
        v4f s0 = {0.f, 0.f, 0.f, 0.f}, s1 = {0.f, 0.f, 0.f, 0.f};
        __builtin_amdgcn_s_setprio(1);
        {
            const int row = mb*16 + l15;
            v8bf kh0 = *(const v8bf*)frag_ptr(&Khi[cur][0], row, quad);
            v8bf kl0 = *(const v8bf*)frag_ptr(&Klo[cur][0], row, quad);
            v8bf kh1 = *(const v8bf*)frag_ptr(&Khi[cur][0], row, 4 + quad);
            v8bf kl1 = *(const v8bf*)frag_ptr(&Klo[cur][0], row, 4 + quad);
            s0 = MFMA16(qhi[0], kh0, s0);
            s1 = MFMA16(qhi[1], kh1, s1);
            s0 = MFMA16(qhi[0], kl0, s0);
            s1 = MFMA16(qhi[1], kl1, s1);
            s0 = MFMA16(qlo[0], kh0, s0);
            s1 = MFMA16(qlo[1], kh1, s1);
        }
        __builtin_amdgcn_s_setprio(0);
        v4f sacc = s0 + s1;

        #pragma unroll
        for (int r = 0; r < 4; ++r) {
            const float p = __expf(sacc[r]);
            lrow[r] += p;
            const int row = quad*4 + r;
            const int slot = (mb*2 + (l15 >> 3)) ^ ((row >> 1) & 3);
            Ps[cur][qt][row*32 + (slot << 3) + (l15 & 7)] = (__bf16)p;
        }

        if (ch) {
            const int pb = nxt;   // (ch-1)&1
            v8bf pa[4];
            #pragma unroll
            for (int t = 0; t < 4; ++t)
                pa[t] = *(const v8bf*)(&Ps[pb][t][0] + l15*32 + ((quad ^ ((l15 >> 1) & 3)) << 3));
            __builtin_amdgcn_s_setprio(1);
            #pragma unroll
            for (int cb = 0; cb < 2; ++cb) {
                const int vrow = w*32 + cb*16 + l15;
                v8bf vv = *(const v8bf*)(&Vs[pb][0] + vrow*32 + ((quad ^ ((vrow >> 1) & 3)) << 3));
                #pragma unroll
                for (int t = 0; t < 4; ++t)
                    oacc[t][cb] = MFMA16(pa[t], vv, oacc[t][cb]);
            }
            __builtin_amdgcn_s_setprio(0);
        }

        asm volatile("s_waitcnt lgkmcnt(0)" ::: "memory");
        #pragma unroll
        for (int j = 0; j < 2; ++j) {
            const int i = w*2 + j;
            __builtin_amdgcn_global_load_lds((gbl_vd*)(Vg + mn*2 + i*32768 + offV),
                                             (lds_vd*)((char*)&Vs[nxt][0] + i*1024), 16, 0, 0);
        }

        asm volatile("s_waitcnt vmcnt(2) lgkmcnt(0)\n\ts_barrier" ::: "memory");
    }

    {
        v8bf pa[4];
        #pragma unroll
        for (int t = 0; t < 4; ++t)
            pa[t] = *(const v8bf*)(&Ps[1][t][0] + l15*32 + ((quad ^ ((l15 >> 1) & 3)) << 3));
        #pragma unroll
        for (int cb = 0; cb < 2; ++cb) {
            const int vrow = w*32 + cb*16 + l15;
            v8bf vv = *(const v8bf*)(&Vs[1][0] + vrow*32 + ((quad ^ ((vrow >> 1) & 3)) << 3));
            #pragma unroll
            for (int t = 0; t < 4; ++t)
                oacc[t][cb] = MFMA16(pa[t], vv, oacc[t][cb]);
        }
    }

    #pragma unroll
    for (int r = 0; r < 4; ++r) {
        float s = lrow[r];
        #pragma unroll
        for (int d = 1; d < 16; d <<= 1) s += __shfl_xor(s, d, 64);
        lrow[r] = s;
    }
    if (l15 == 0) {
        #pragma unroll
        for (int r = 0; r < 4; ++r) lsh[mb][qt][quad*4 + r] = lrow[r];
    }
    __syncthreads();

    const float scl = scale_p[0];
    float inv[4][4];
    #pragma unroll
    for (int t = 0; t < 4; ++t)
        #pragma unroll
        for (int r = 0; r < 4; ++r)
            inv[t][r] = scl / (lsh[0][t][quad*4 + r] + lsh[1][t][quad*4 + r]);
    float* outb = out + (size_t)b * 256 * 4096;
    #pragma unroll
    for (int cb = 0; cb < 2; ++cb) {
        const int c = w*32 + cb*16 + l15;
        #pragma unroll
        for (int t = 0; t < 4; ++t) {
            float4 v;
            v.x = oacc[t][cb][0] * inv[t][0];
            v.y = oacc[t][cb][1] * inv[t][1];
            v.z = oacc[t][cb][2] * inv[t][2];
            v.w = oacc[t][cb][3] * inv[t][3];
            *(float4*)(outb + (size_t)c * 4096 + q0 + t*16 + quad*4) = v;
        }
    }
}

// ===========================================================================
extern "C" void kernel_launch(void* const* d_in, const int* in_sizes, int n_in,
                              void* d_out, int out_size, void* d_ws, size_t ws_size,
                              hipStream_t stream)
{
    const float* fms_low  = (const float*)d_in[0];
    const float* fms_high = (const float*)d_in[1];
    const float* w_conv   = (const float*)d_in[2];
    const float* gamma    = (const float*)d_in[3];
    const float* beta     = (const float*)d_in[4];
    const float* mean     = (const float*)d_in[5];
    const float* var      = (const float*)d_in[6];
    const float* fc1_w    = (const float*)d_in[7];
    const float* fc1_b    = (const float*)d_in[8];
    const float* fc2_w    = (const float*)d_in[9];
    const float* fc2_b    = (const float*)d_in[10];
    const float* scale    = (const float*)d_in[11];
    float* out = (float*)d_out;

    __bf16* Xhi  = (__bf16*)d_ws;
    __bf16* Xlo  = Xhi  + (size_t)8*256*1024;
    __bf16* VT   = Xlo  + (size_t)8*256*1024;
    __bf16* MLhi = VT   + (size_t)8*256*1024;
    __bf16* MLlo = MLhi + (size_t)8*4096*64;
    __bf16* MHhi = MLlo + (size_t)8*4096*64;
    __bf16* MHlo = MHhi + (size_t)8*1024*64;

    k_conv<<<dim3(16, 4, 8), 256, 0, stream>>>(fms_high, w_conv, gamma, beta,
                                               mean, var, Xhi, Xlo, VT);
    k_proj<<<dim3(320), 512, 0, stream>>>(fms_low, Xhi, Xlo,
                                          fc1_w, fc1_b, fc2_w, fc2_b,
                                          MLhi, MLlo, MHhi, MHlo);
    k_attn<<<dim3(512), 512, 0, stream>>>(MLhi, MLlo, MHhi, MHlo, VT, scale, out);
}

// Round 9
// 176.407 us; speedup vs baseline: 1.0637x; 1.0143x over previous
//
#include <hip/hip_runtime.h>
#include <hip/hip_bf16.h>

typedef __bf16 v8bf __attribute__((ext_vector_type(8)));
typedef float  v4f  __attribute__((ext_vector_type(4)));

typedef __attribute__((address_space(3))) void       lds_vd;
typedef __attribute__((address_space(1))) const void gbl_vd;

#define MFMA16(a, b, c) __builtin_amdgcn_mfma_f32_16x16x32_bf16(a, b, c, 0, 0, 0)

// hi/lo bf16 split of an fp32 value (hi = RN(v), lo = RN(v - hi))
__device__ __forceinline__ void split_hl(float v, __bf16* h, __bf16* l) {
    __bf16 hh = (__bf16)v;
    *h = hh;
    *l = (__bf16)(v - (float)hh);
}

// XOR-swizzled [R][64] bf16 LDS tiles: element (row,col) lives at
// row*64 + ((col>>3 ^ (row&7))<<3) + (col&7).
__device__ __forceinline__ int swz_idx(int row, int col) {
    return row * 64 + ((((col >> 3) ^ (row & 7))) << 3) + (col & 7);
}
__device__ __forceinline__ const __bf16* frag_ptr(const __bf16* base, int row, int g) {
    return base + row * 64 + ((g ^ (row & 7)) << 3);
}

// ---------------------------------------------------------------------------
// dims: fms_low [8][256][64][64] -> feat_low [8·4096][256] (flat view)
//       fms_high [8][512][32][32]; conv -> X [8][256][1024] = feat_high [8·1024][256]
//       ML [8·4096][64] hi/lo, MH [8·1024][64] hi/lo, VT [8][256][1024]
//       out [8][256][4096]
// ---------------------------------------------------------------------------

// ================= conv + BN + ReLU (hi/lo bf16 MFMA GEMM) =================
// (R3/R5-verified version, verbatim)
__global__ __launch_bounds__(256) void k_conv(
    const float* __restrict__ FH, const float* __restrict__ W,
    const float* __restrict__ gamma, const float* __restrict__ beta,
    const float* __restrict__ mean, const float* __restrict__ var,
    __bf16* __restrict__ Xhi, __bf16* __restrict__ Xlo, __bf16* __restrict__ VT)
{
    __shared__ __align__(16) __bf16 Ah[64 * 64];  // W tile hi
    __shared__ __align__(16) __bf16 Al[64 * 64];
    __shared__ __align__(16) __bf16 Bh[64 * 64];  // FH^T tile hi (rows n = pv*16+ul)
    __shared__ __align__(16) __bf16 Bl[64 * 64];
    __shared__ float invl[64], shl[64];

    const int tid = threadIdx.x, lane = tid & 63, w = tid >> 6;
    const int l15 = lane & 15, quad = lane >> 4;
    const int u0 = blockIdx.x * 16, o0 = blockIdx.y * 64, b = blockIdx.z;
    const float* FHb = FH + (size_t)b * 524288;

    if (tid < 64) {
        const int o = o0 + tid;
        const float iv = gamma[o] * rsqrtf(var[o] + 1e-5f);
        invl[tid] = iv;
        shl[tid] = beta[o] - mean[o] * iv;
    }

    const int ao = tid >> 2, aseg = tid & 3;   // A staging: W row, 16-col segment
    float wreg[16], freg[16];
    {   // prefetch chunk 0
        const float* wp = W + (size_t)(o0 + ao) * 512 + aseg * 16;
        #pragma unroll
        for (int q = 0; q < 4; ++q) {
            float4 f = ((const float4*)wp)[q];
            wreg[4*q] = f.x; wreg[4*q+1] = f.y; wreg[4*q+2] = f.z; wreg[4*q+3] = f.w;
        }
        const float* fp = FHb + (size_t)lane * 1024 + w * 256 + u0;
        #pragma unroll
        for (int q = 0; q < 4; ++q) {
            float4 f = ((const float4*)fp)[q];
            freg[4*q] = f.x; freg[4*q+1] = f.y; freg[4*q+2] = f.z; freg[4*q+3] = f.w;
        }
    }

    v4f acc[2][2];
    #pragma unroll
    for (int i = 0; i < 2; ++i)
        #pragma unroll
        for (int j = 0; j < 2; ++j) { v4f z = {0.f,0.f,0.f,0.f}; acc[i][j] = z; }
    const int oh = w >> 1, nh = w & 1;

    for (int ch = 0; ch < 8; ++ch) {
        if (ch) __syncthreads();
        #pragma unroll
        for (int z = 0; z < 2; ++z) {
            v8bf hv, lv;
            #pragma unroll
            for (int e = 0; e < 8; ++e) {
                __bf16 h, l; split_hl(wreg[8*z + e], &h, &l);
                hv[e] = h; lv[e] = l;
            }
            const int gi = (2*aseg + z) ^ (ao & 7);
            *(v8bf*)(Ah + ao*64 + (gi << 3)) = hv;
            *(v8bf*)(Al + ao*64 + (gi << 3)) = lv;
        }
        #pragma unroll
        for (int ul = 0; ul < 16; ++ul) {
            __bf16 h, l; split_hl(freg[ul], &h, &l);
            const int idx = (w*16 + ul)*64 + (((lane >> 3) ^ (ul & 7)) << 3) + (lane & 7);
            Bh[idx] = h; Bl[idx] = l;
        }
        __syncthreads();
        if (ch < 7) {
            const int c1 = (ch + 1) * 64;
            const float* wp = W + (size_t)(o0 + ao) * 512 + c1 + aseg * 16;
            #pragma unroll
            for (int q = 0; q < 4; ++q) {
                float4 f = ((const float4*)wp)[q];
                wreg[4*q] = f.x; wreg[4*q+1] = f.y; wreg[4*q+2] = f.z; wreg[4*q+3] = f.w;
            }
            const float* fp = FHb + (size_t)(c1 + lane) * 1024 + w * 256 + u0;
            #pragma unroll
            for (int q = 0; q < 4; ++q) {
                float4 f = ((const float4*)fp)[q];
                freg[4*q] = f.x; freg[4*q+1] = f.y; freg[4*q+2] = f.z; freg[4*q+3] = f.w;
            }
        }
        #pragma unroll
        for (int ks = 0; ks < 2; ++ks) {
            const int g = 4*ks + quad;
            v8bf a_h[2], a_l[2], b_h[2], b_l[2];
            #pragma unroll
            for (int i = 0; i < 2; ++i) {
                const int row = oh*32 + i*16 + l15;
                a_h[i] = *(const v8bf*)frag_ptr(Ah, row, g);
                a_l[i] = *(const v8bf*)frag_ptr(Al, row, g);
            }
            #pragma unroll
            for (int j = 0; j < 2; ++j) {
                const int row = nh*32 + j*16 + l15;
                b_h[j] = *(const v8bf*)frag_ptr(Bh, row, g);
                b_l[j] = *(const v8bf*)frag_ptr(Bl, row, g);
            }
            #pragma unroll
            for (int i = 0; i < 2; ++i)
                #pragma unroll
                for (int j = 0; j < 2; ++j) {
                    acc[i][j] = MFMA16(a_h[i], b_h[j], acc[i][j]);
                    acc[i][j] = MFMA16(a_h[i], b_l[j], acc[i][j]);
                    acc[i][j] = MFMA16(a_l[i], b_h[j], acc[i][j]);
                }
        }
    }
    __syncthreads();

    #pragma unroll
    for (int i = 0; i < 2; ++i)
        #pragma unroll
        for (int j = 0; j < 2; ++j)
            #pragma unroll
            for (int r = 0; r < 4; ++r) {
                const int row = oh*32 + i*16 + quad*4 + r;
                const int col = nh*32 + j*16 + l15;
                float v = acc[i][j][r] * invl[row] + shl[row];
                v = fmaxf(v, 0.f);
                __bf16 h, l; split_hl(v, &h, &l);
                const int idx = swz_idx(row, col);
                Ah[idx] = h; Al[idx] = l;
            }
    __syncthreads();
    {
        const int o = tid >> 2, pv = tid & 3;
        const size_t gbase = ((size_t)b*256 + o0 + o) * 1024 + pv*256 + u0;
        #pragma unroll
        for (int z = 0; z < 2; ++z) {
            const int gi = (2*pv + z) ^ (o & 7);
            v8bf h = *(v8bf*)(Ah + o*64 + (gi << 3));
            v8bf l = *(v8bf*)(Al + o*64 + (gi << 3));
            *(v8bf*)(Xhi + gbase + z*8) = h;
            *(v8bf*)(Xlo + gbase + z*8) = l;
        }
    }
    {
        const int ul = tid >> 4, s = tid & 15;
        __bf16 tmp[16];
        #pragma unroll
        for (int k = 0; k < 16; ++k) {
            const int m = s*16 + k;
            const int row = m >> 2;
            const int col = (m & 3)*16 + ul;
            tmp[k] = Ah[swz_idx(row, col)];
        }
        __bf16* vp = VT + ((size_t)b*256 + u0 + ul) * 1024 + 4*o0 + s*16;
        *(v8bf*)(vp)     = *(v8bf*)(tmp);
        *(v8bf*)(vp + 8) = *(v8bf*)(tmp + 8);
    }
}

// ================ merged projections, 8-wave blocks (verbatim R7) ==========
__global__ __launch_bounds__(512) void k_proj(
    const float* __restrict__ Feat,                     // ML A (fp32)
    const __bf16* __restrict__ Fhi, const __bf16* __restrict__ Flo,  // MH A
    const float* __restrict__ W1, const float* __restrict__ b1,
    const float* __restrict__ W2, const float* __restrict__ b2,
    __bf16* __restrict__ O1hi, __bf16* __restrict__ O1lo,
    __bf16* __restrict__ O2hi, __bf16* __restrict__ O2lo)
{
    __shared__ __align__(16) __bf16 Bh[64 * 256];   // 32 KB  [n][k granule-swz]
    __shared__ __align__(16) __bf16 Bl[64 * 256];   // 32 KB
    __shared__ __align__(16) __bf16 Eo[8][16 * 64]; // 16 KB  per-wave epilogue

    const int tid = threadIdx.x, lane = tid & 63, w = tid >> 6;   // w: 0..7
    const int l15 = lane & 15, quad = lane >> 4;
    const bool low = blockIdx.x < 256;
    const int r0 = (low ? blockIdx.x : (blockIdx.x - 256)) * 128;
    const int row = r0 + w*16 + l15;

    const float* Wfc = low ? W1 : W2;
    const float* bfc = low ? b1 : b2;
    __bf16* Ohi = low ? O1hi : O2hi;
    __bf16* Olo = low ? O1lo : O2lo;

    {
        const int n = tid >> 3, q8 = tid & 7, n7 = n & 7;
        const float* wp = Wfc + (size_t)n * 256 + q8 * 32;
        #pragma unroll
        for (int z = 0; z < 4; ++z) {
            float4 f0 = ((const float4*)wp)[2*z];
            float4 f1 = ((const float4*)wp)[2*z + 1];
            float w8[8] = {f0.x, f0.y, f0.z, f0.w, f1.x, f1.y, f1.z, f1.w};
            v8bf hv, lv;
            #pragma unroll
            for (int e = 0; e < 8; ++e) {
                __bf16 h, l; split_hl(w8[e], &h, &l);
                hv[e] = h; lv[e] = l;
            }
            const int gsw = (q8*4 + z) ^ n7;
            *(v8bf*)(Bh + n*256 + gsw*8) = hv;
            *(v8bf*)(Bl + n*256 + gsw*8) = lv;
        }
    }
    __syncthreads();   // only barrier: B visible; read-only afterwards

    v4f acc[4];
    #pragma unroll
    for (int j = 0; j < 4; ++j) { v4f z = {0.f,0.f,0.f,0.f}; acc[j] = z; }

    const int l7 = l15 & 7;
    const __bf16* bh_base = Bh + l15*256;
    const __bf16* bl_base = Bl + l15*256;

    if (low) {
        const float* ap = Feat + (size_t)row * 256 + quad * 8;
        float acur[8], anxt[8];
        {
            float4 f0 = ((const float4*)ap)[0];
            float4 f1 = ((const float4*)ap)[1];
            acur[0]=f0.x; acur[1]=f0.y; acur[2]=f0.z; acur[3]=f0.w;
            acur[4]=f1.x; acur[5]=f1.y; acur[6]=f1.z; acur[7]=f1.w;
        }
        #pragma unroll
        for (int kc = 0; kc < 8; ++kc) {
            if (kc < 7) {
                float4 f0 = ((const float4*)(ap + (kc+1)*32))[0];
                float4 f1 = ((const float4*)(ap + (kc+1)*32))[1];
                anxt[0]=f0.x; anxt[1]=f0.y; anxt[2]=f0.z; anxt[3]=f0.w;
                anxt[4]=f1.x; anxt[5]=f1.y; anxt[6]=f1.z; anxt[7]=f1.w;
            }
            v8bf ah, al;
            #pragma unroll
            for (int e = 0; e < 8; ++e) {
                __bf16 h, l; split_hl(acur[e], &h, &l);
                ah[e] = h; al[e] = l;
            }
            const int goff = (((kc*4 + quad) ^ l7) << 3);
            #pragma unroll
            for (int j = 0; j < 4; ++j) {
                v8bf bh = *(const v8bf*)(bh_base + j*4096 + goff);
                v8bf bl = *(const v8bf*)(bl_base + j*4096 + goff);
                acc[j] = MFMA16(ah, bh, acc[j]);
                acc[j] = MFMA16(ah, bl, acc[j]);
                acc[j] = MFMA16(al, bh, acc[j]);
            }
            #pragma unroll
            for (int e = 0; e < 8; ++e) acur[e] = anxt[e];
        }
    } else {
        const __bf16* fh = Fhi + (size_t)row * 256 + quad * 8;
        const __bf16* fl = Flo + (size_t)row * 256 + quad * 8;
        v8bf ah = *(const v8bf*)(fh);
        v8bf al = *(const v8bf*)(fl);
        #pragma unroll
        for (int kc = 0; kc < 8; ++kc) {
            v8bf anh, anl;
            if (kc < 7) {
                anh = *(const v8bf*)(fh + (kc+1)*32);
                anl = *(const v8bf*)(fl + (kc+1)*32);
            }
            const int goff = (((kc*4 + quad) ^ l7) << 3);
            #pragma unroll
            for (int j = 0; j < 4; ++j) {
                v8bf bh = *(const v8bf*)(bh_base + j*4096 + goff);
                v8bf bl = *(const v8bf*)(bl_base + j*4096 + goff);
                acc[j] = MFMA16(ah, bh, acc[j]);
                acc[j] = MFMA16(ah, bl, acc[j]);
                acc[j] = MFMA16(al, bh, acc[j]);
            }
            if (kc < 7) { ah = anh; al = anl; }
        }
    }

    __bf16* eo = &Eo[w][0];
    __bf16 lb[4][4];
    #pragma unroll
    for (int j = 0; j < 4; ++j) {
        const float bias = bfc[j*16 + l15];
        #pragma unroll
        for (int r = 0; r < 4; ++r) {
            __bf16 h, l; split_hl(acc[j][r] + bias, &h, &l);
            lb[j][r] = l;
            eo[swz_idx(quad*4 + r, j*16 + l15)] = h;
        }
    }
    const size_t orow = (size_t)row * 64;
    #pragma unroll
    for (int z = 0; z < 2; ++z) {
        const int gi = (2*quad + z) ^ l7;
        *(v8bf*)(Ohi + orow + quad*16 + z*8) = *(v8bf*)(eo + l15*64 + gi*8);
    }
    #pragma unroll
    for (int j = 0; j < 4; ++j)
        #pragma unroll
        for (int r = 0; r < 4; ++r)
            eo[swz_idx(quad*4 + r, j*16 + l15)] = lb[j][r];
    #pragma unroll
    for (int z = 0; z < 2; ++z) {
        const int gi = (2*quad + z) ^ l7;
        *(v8bf*)(Olo + orow + quad*16 + z*8) = *(v8bf*)(eo + l15*64 + gi*8);
    }
}

// ============================= flash attention =============================
// R7 structure + K TRIPLE-buffering: the bottom barrier previously had to
// retire K[ch+1] issued at the top of the SAME iteration (vmcnt(2) ledger) —
// one exposed L2 round trip per iteration.  Now K[ch+2] is issued each
// iteration into a 3-deep rotation, so every load the barrier waits on is
// >= 1 full iteration old.  Ledger at loop bottom (oldest->newest):
//   [K[ch+1] (iter ch-1), V[ch]x2 (iter ch-1), K[ch+2], V[ch+1]x2] = 6
//   required retired: K[ch+1] (QK next iter), V[ch]x2 (PV next iter)
//   -> s_waitcnt vmcnt(3).
// Prologue stages K[0],K[1],V[0] and waits vmcnt(3) (retires K[0] only).
// K-buffer write hazard: buf (ch+2)%3 was read by QK(ch-1), drained by the
// lgkmcnt(0)+barrier at bottom of iter ch-1, strictly before this stage.
// LDS 64.5 KB -> still 2 blocks/CU.  All numerics identical to R5/R7.
__global__ __launch_bounds__(512, 4) void k_attn(
    const __bf16* __restrict__ MLhi, const __bf16* __restrict__ MLlo,
    const __bf16* __restrict__ MHhi, const __bf16* __restrict__ MHlo,
    const __bf16* __restrict__ VT,   // [b][256][1024]
    const float* __restrict__ scale_p,
    float* __restrict__ out)
{
    __shared__ __align__(16) __bf16 Khi[3][32 * 64];   // 12 KB [buf][m][k]
    __shared__ __align__(16) __bf16 Klo[3][32 * 64];   // 12 KB
    __shared__ __align__(16) __bf16 Vs [2][256 * 32];  // 32 KB [buf][c][m_local]
    __shared__ __align__(16) __bf16 Ps [2][4][16 * 32];// 8 KB  [buf][qt][q][m]
    __shared__ float lsh[2][4][16];                    // [mb][qt][row]

    const int tid = threadIdx.x, lane = tid & 63, w = tid >> 6;   // w: 0..7
    const int l15 = lane & 15, quad = lane >> 4;
    const int b = blockIdx.x & 7, qtb = blockIdx.x >> 3;
    const int q0 = qtb * 64;
    const int qt = w & 3, mb = w >> 2;

    v8bf qhi[2], qlo[2];
    {
        const __bf16* qp  = MLhi + ((size_t)(b*4096 + q0 + qt*16 + l15)) * 64;
        const __bf16* qlp = MLlo + ((size_t)(b*4096 + q0 + qt*16 + l15)) * 64;
        #pragma unroll
        for (int h = 0; h < 2; ++h) {
            qhi[h] = *(const v8bf*)(qp + h*32 + quad*8);
            qlo[h] = *(const v8bf*)(qlp + h*32 + quad*8);
        }
    }
    #pragma unroll
    for (int h = 0; h < 2; ++h) {
        asm volatile("" : "+v"(qhi[h]));
        asm volatile("" : "+v"(qlo[h]));
    }

    const char* Khg = (const char*)(MHhi + (size_t)b * 65536);
    const char* Klg = (const char*)(MHlo + (size_t)b * 65536);
    const char* Vg  = (const char*)(VT + (size_t)b * 262144);
    const int offK = (lane >> 3) * 128 + (((lane & 7) ^ ((lane >> 3) & 7)) << 4);
    const int offV = (lane >> 2) * 2048 + ((((lane & 3) ^ ((lane >> 3) & 3))) << 4);

    const char* kgsrc = (w < 4) ? Khg : Klg;           // waves 0-3: hi, 4-7: lo
    const int ksub = (w & 3) * 1024;                   // 8-row slice
    char* kdst_base = (char*)((w < 4) ? &Khi[0][0] : &Klo[0][0]);

    v4f oacc[4][2];
    #pragma unroll
    for (int t = 0; t < 4; ++t)
        #pragma unroll
        for (int cb = 0; cb < 2; ++cb) { v4f z = {0.f,0.f,0.f,0.f}; oacc[t][cb] = z; }
    float lrow[4] = {0.f, 0.f, 0.f, 0.f};

    // ---- prologue: K[0] -> buf0, K[1] -> buf1, V[0] -> buf0
    {
        __builtin_amdgcn_global_load_lds((gbl_vd*)(kgsrc + ksub + offK),
                                         (lds_vd*)(kdst_base + ksub), 16, 0, 0);
        __builtin_amdgcn_global_load_lds((gbl_vd*)(kgsrc + 4096 + ksub + offK),
                                         (lds_vd*)(kdst_base + 4096 + ksub), 16, 0, 0);
        #pragma unroll
        for (int j = 0; j < 2; ++j) {
            const int i = w*2 + j;
            __builtin_amdgcn_global_load_lds((gbl_vd*)(Vg + i*32768 + offV),
                                             (lds_vd*)((char*)&Vs[0][0] + i*1024), 16, 0, 0);
        }
    }
    // retire K[0] only (K[1], V[0]x2 stay in flight), then all-waves sync.
    asm volatile("s_waitcnt vmcnt(3)\n\ts_barrier" ::: "memory");

    int kb = 0;   // K buffer holding K[ch]
    for (int ch = 0; ch < 32; ++ch) {
        const int cur = ch & 1, nxt = cur ^ 1;
        const int mn  = ((ch < 31) ? (ch + 1) : 31) * 32;   // V restage (clamped)
        const int mn2 = ((ch < 30) ? (ch + 2) : 31) * 32;   // K stage (clamped)
        const int sd  = (kb >= 1) ? (kb - 1) : 2;           // (kb+2)%3

        // a) stage K[ch+2] into buf sd (1 inst/wave)
        __builtin_amdgcn_global_load_lds((gbl_vd*)(kgsrc + mn2*128 + ksub + offK),
                                         (lds_vd*)(kdst_base + sd*4096 + ksub), 16, 0, 0);

        // b) QK(ch): two independent 3-chains, combined at the end
        v4f s0 = {0.f, 0.f, 0.f, 0.f}, s1 = {0.f, 0.f, 0.f, 0.f};
        __builtin_amdgcn_s_setprio(1);
        {
            const int row = mb*16 + l15;
            v8bf kh0 = *(const v8bf*)frag_ptr(&Khi[kb][0], row, quad);
            v8bf kl0 = *(const v8bf*)frag_ptr(&Klo[kb][0], row, quad);
            v8bf kh1 = *(const v8bf*)frag_ptr(&Khi[kb][0], row, 4 + quad);
            v8bf kl1 = *(const v8bf*)frag_ptr(&Klo[kb][0], row, 4 + quad);
            s0 = MFMA16(qhi[0], kh0, s0);
            s1 = MFMA16(qhi[1], kh1, s1);
            s0 = MFMA16(qhi[0], kl0, s0);
            s1 = MFMA16(qhi[1], kl1, s1);
            s0 = MFMA16(qlo[0], kh0, s0);
            s1 = MFMA16(qlo[1], kh1, s1);
        }
        __builtin_amdgcn_s_setprio(0);
        v4f sacc = s0 + s1;

        #pragma unroll
        for (int r = 0; r < 4; ++r) {
            const float p = __expf(sacc[r]);
            lrow[r] += p;
            const int row = quad*4 + r;
            const int slot = (mb*2 + (l15 >> 3)) ^ ((row >> 1) & 3);
            Ps[cur][qt][row*32 + (slot << 3) + (l15 & 7)] = (__bf16)p;
        }

        // c) PV(ch-1): wave w covers c in [w*32, +32)
        if (ch) {
            const int pb = nxt;   // (ch-1)&1
            v8bf pa[4];
            #pragma unroll
            for (int t = 0; t < 4; ++t)
                pa[t] = *(const v8bf*)(&Ps[pb][t][0] + l15*32 + ((quad ^ ((l15 >> 1) & 3)) << 3));
            __builtin_amdgcn_s_setprio(1);
            #pragma unroll
            for (int cb = 0; cb < 2; ++cb) {
                const int vrow = w*32 + cb*16 + l15;
                v8bf vv = *(const v8bf*)(&Vs[pb][0] + vrow*32 + ((quad ^ ((vrow >> 1) & 3)) << 3));
                #pragma unroll
                for (int t = 0; t < 4; ++t)
                    oacc[t][cb] = MFMA16(pa[t], vv, oacc[t][cb]);
            }
            __builtin_amdgcn_s_setprio(0);
        }

        // d) re-stage V[ch+1] into buf nxt (wave-local).  Fence: this wave's
        // Vs[nxt] ds_reads (PV above) must retire before the DMA overwrites.
        asm volatile("s_waitcnt lgkmcnt(0)" ::: "memory");
        #pragma unroll
        for (int j = 0; j < 2; ++j) {
            const int i = w*2 + j;
            __builtin_amdgcn_global_load_lds((gbl_vd*)(Vg + mn*2 + i*32768 + offV),
                                             (lds_vd*)((char*)&Vs[nxt][0] + i*1024), 16, 0, 0);
        }

        // e) single barrier/iter: retire K[ch+1] + V[ch]x2 (>=1 iter old);
        //    K[ch+2] + V[ch+1]x2 stay in flight.
        asm volatile("s_waitcnt vmcnt(3) lgkmcnt(0)\n\ts_barrier" ::: "memory");

        kb = (kb < 2) ? (kb + 1) : 0;
    }

    // ---- epilogue PV(31) (Ps[1]/Vs[1]; V[31] retired by last loop barrier)
    {
        v8bf pa[4];
        #pragma unroll
        for (int t = 0; t < 4; ++t)
            pa[t] = *(const v8bf*)(&Ps[1][t][0] + l15*32 + ((quad ^ ((l15 >> 1) & 3)) << 3));
        #pragma unroll
        for (int cb = 0; cb < 2; ++cb) {
            const int vrow = w*32 + cb*16 + l15;
            v8bf vv = *(const v8bf*)(&Vs[1][0] + vrow*32 + ((quad ^ ((vrow >> 1) & 3)) << 3));
            #pragma unroll
            for (int t = 0; t < 4; ++t)
                oacc[t][cb] = MFMA16(pa[t], vv, oacc[t][cb]);
        }
    }

    #pragma unroll
    for (int r = 0; r < 4; ++r) {
        float s = lrow[r];
        #pragma unroll
        for (int d = 1; d < 16; d <<= 1) s += __shfl_xor(s, d, 64);
        lrow[r] = s;
    }
    if (l15 == 0) {
        #pragma unroll
        for (int r = 0; r < 4; ++r) lsh[mb][qt][quad*4 + r] = lrow[r];
    }
    __syncthreads();

    const float scl = scale_p[0];
    float inv[4][4];
    #pragma unroll
    for (int t = 0; t < 4; ++t)
        #pragma unroll
        for (int r = 0; r < 4; ++r)
            inv[t][r] = scl / (lsh[0][t][quad*4 + r] + lsh[1][t][quad*4 + r]);
    float* outb = out + (size_t)b * 256 * 4096;
    #pragma unroll
    for (int cb = 0; cb < 2; ++cb) {
        const int c = w*32 + cb*16 + l15;
        #pragma unroll
        for (int t = 0; t < 4; ++t) {
            float4 v;
            v.x = oacc[t][cb][0] * inv[t][0];
            v.y = oacc[t][cb][1] * inv[t][1];
            v.z = oacc[t][cb][2] * inv[t][2];
            v.w = oacc[t][cb][3] * inv[t][3];
            *(float4*)(outb + (size_t)c * 4096 + q0 + t*16 + quad*4) = v;
        }
    }
}

// ===========================================================================
extern "C" void kernel_launch(void* const* d_in, const int* in_sizes, int n_in,
                              void* d_out, int out_size, void* d_ws, size_t ws_size,
                              hipStream_t stream)
{
    const float* fms_low  = (const float*)d_in[0];
    const float* fms_high = (const float*)d_in[1];
    const float* w_conv   = (const float*)d_in[2];
    const float* gamma    = (const float*)d_in[3];
    const float* beta     = (const float*)d_in[4];
    const float* mean     = (const float*)d_in[5];
    const float* var      = (const float*)d_in[6];
    const float* fc1_w    = (const float*)d_in[7];
    const float* fc1_b    = (const float*)d_in[8];
    const float* fc2_w    = (const float*)d_in[9];
    const float* fc2_b    = (const float*)d_in[10];
    const float* scale    = (const float*)d_in[11];
    float* out = (float*)d_out;

    __bf16* Xhi  = (__bf16*)d_ws;
    __bf16* Xlo  = Xhi  + (size_t)8*256*1024;
    __bf16* VT   = Xlo  + (size_t)8*256*1024;
    __bf16* MLhi = VT   + (size_t)8*256*1024;
    __bf16* MLlo = MLhi + (size_t)8*4096*64;
    __bf16* MHhi = MLlo + (size_t)8*4096*64;
    __bf16* MHlo = MHhi + (size_t)8*1024*64;

    k_conv<<<dim3(16, 4, 8), 256, 0, stream>>>(fms_high, w_conv, gamma, beta,
                                               mean, var, Xhi, Xlo, VT);
    k_proj<<<dim3(320), 512, 0, stream>>>(fms_low, Xhi, Xlo,
                                          fc1_w, fc1_b, fc2_w, fc2_b,
                                          MLhi, MLlo, MHhi, MHlo);
    k_attn<<<dim3(512), 512, 0, stream>>>(MLhi, MLlo, MHhi, MHlo, VT, scale, out);
}